// Round 5
// baseline (253.369 us; speedup 1.0000x reference)
//
#include <hip/hip_runtime.h>
#include <hip/hip_bf16.h>
#include <cstdint>
#include <cstddef>

// YatAttention on MI355X (gfx950).
// B=2, L=2048, E=768, H=12, D=64. GEMMs in bf16 MFMA 16x16x32 (fp32 accum).
// R5: S=1 (grid 768 = exact 3 blocks/CU single pass at the LDS-limited
// occupancy) -> k_attn writes normalized AO directly (k_merge + 50MB partial
// traffic gone); k_gemm_qkv writes VT directly (k_vt gone); mask folded into
// ksq sign (int4 mask loads gone). k_attn inner loop unchanged from R4.

typedef __bf16 bf16_t;
typedef __bf16 bf16x8 __attribute__((ext_vector_type(8)));
typedef __bf16 bf16x4 __attribute__((ext_vector_type(4)));
typedef float floatx4 __attribute__((ext_vector_type(4)));

#define DEVI static __device__ __forceinline__

#define Bc 2
#define Lc 2048
#define Ec 768
#define Hc 12
#define Dc 64
#define N3c 2304
#define Mc 4096
#define ROWSc (Bc * Hc * Lc)  // 49152

DEVI void glds16(const bf16_t* g, bf16_t* l) {
  __builtin_amdgcn_global_load_lds(
      (const __attribute__((address_space(1))) void*)g,
      (__attribute__((address_space(3))) void*)l, 16, 0, 0);
}

// ---------------- conversion kernels ----------------

__global__ __launch_bounds__(256) void k_cvt(const float* __restrict__ in,
                                             bf16_t* __restrict__ out, int n) {
  int i = (blockIdx.x * 256 + threadIdx.x) * 4;
  if (i >= n) return;
  float4 v = *(const float4*)(in + i);
  bf16x4 o;
  o[0] = (bf16_t)v.x; o[1] = (bf16_t)v.y; o[2] = (bf16_t)v.z; o[3] = (bf16_t)v.w;
  *(bf16x4*)(out + i) = o;
}

__global__ __launch_bounds__(256) void k_tc(const float* __restrict__ in,
                                            bf16_t* __restrict__ out, int R, int C) {
  __shared__ float tile[32][33];
  int c0 = blockIdx.x * 32, r0 = blockIdx.y * 32;
  int tx = threadIdx.x, ty = threadIdx.y;
  #pragma unroll
  for (int i = 0; i < 32; i += 8)
    tile[ty + i][tx] = in[(size_t)(r0 + ty + i) * C + c0 + tx];
  __syncthreads();
  #pragma unroll
  for (int i = 0; i < 32; i += 8)
    out[(size_t)(c0 + ty + i) * R + r0 + tx] = (bf16_t)tile[tx][ty + i];
}

// ---------------- GEMM core (m97 pattern) ----------------

DEVI void gemm_core(const bf16_t* __restrict__ A, const bf16_t* __restrict__ Bt,
                    bf16_t* lA, bf16_t* lB, int m0, int n0, floatx4 (&acc)[4][4]) {
  const int tid = threadIdx.x, wave = tid >> 6, lane = tid & 63;
  const int wm = (wave >> 1) * 64, wn = (wave & 1) * 64;
  const int lrow = lane >> 2, lseg = lane & 3;
  const int quad = lane >> 4, r16 = lane & 15;
  for (int kk = 0; kk < 768; kk += 32) {
    glds16(A  + (size_t)(m0 + wave * 32      + lrow) * 768 + kk + lseg * 8, lA + (wave * 32) * 32);
    glds16(A  + (size_t)(m0 + wave * 32 + 16 + lrow) * 768 + kk + lseg * 8, lA + (wave * 32 + 16) * 32);
    glds16(Bt + (size_t)(n0 + wave * 32      + lrow) * 768 + kk + lseg * 8, lB + (wave * 32) * 32);
    glds16(Bt + (size_t)(n0 + wave * 32 + 16 + lrow) * 768 + kk + lseg * 8, lB + (wave * 32 + 16) * 32);
    __syncthreads();
    bf16x8 af[4], bv[4];
    #pragma unroll
    for (int mi = 0; mi < 4; mi++)
      af[mi] = *(const bf16x8*)(lA + (wm + mi * 16 + r16) * 32 + quad * 8);
    #pragma unroll
    for (int ni = 0; ni < 4; ni++)
      bv[ni] = *(const bf16x8*)(lB + (wn + ni * 16 + r16) * 32 + quad * 8);
    #pragma unroll
    for (int mi = 0; mi < 4; mi++)
      #pragma unroll
      for (int ni = 0; ni < 4; ni++)
        acc[mi][ni] = __builtin_amdgcn_mfma_f32_16x16x32_bf16(af[mi], bv[ni], acc[mi][ni], 0, 0, 0);
    __syncthreads();
  }
}

// QKV GEMM. Q,K sections -> (B,H,L,D); V section -> VT (B,H,D,L) directly.
__global__ __launch_bounds__(256) void k_gemm_qkv(
    const bf16_t* __restrict__ A, const bf16_t* __restrict__ Bt,
    const float* __restrict__ bias,
    bf16_t* __restrict__ Qo, bf16_t* __restrict__ Ko, bf16_t* __restrict__ VTo) {
  __shared__ bf16_t lA[128 * 32];
  __shared__ bf16_t lB[128 * 32];
  const int m0 = blockIdx.y * 128, n0 = blockIdx.x * 128;
  const int tid = threadIdx.x, wave = tid >> 6, lane = tid & 63;
  const int wm = (wave >> 1) * 64, wn = (wave & 1) * 64;
  const int quad = lane >> 4, r16 = lane & 15;
  floatx4 acc[4][4] = {};
  gemm_core(A, Bt, lA, lB, m0, n0, acc);

  const int sec = n0 / 768;  // block-uniform: 6 full 128-tiles per section
  if (sec == 2) {
    // V: write transposed. Lane owns col n (-> h,d fixed per ni), rows l
    // contiguous in reg -> bf16x4 stores.
    #pragma unroll
    for (int ni = 0; ni < 4; ni++) {
      const int n = n0 + wn + ni * 16 + r16;
      const int nn = n - 1536;
      const int h = nn >> 6, d = nn & 63;
      const float bvs = bias[n];
      #pragma unroll
      for (int mi = 0; mi < 4; mi++) {
        const int m = m0 + wm + mi * 16 + quad * 4;
        const int b = m >> 11, l = m & 2047;
        bf16x4 o;
        #pragma unroll
        for (int reg = 0; reg < 4; reg++) o[reg] = (bf16_t)(acc[mi][ni][reg] + bvs);
        *(bf16x4*)(VTo + ((size_t)(b * Hc + h) * Dc + d) * Lc + l) = o;
      }
    }
  } else {
    bf16_t* dst = (sec == 0) ? Qo : Ko;
    #pragma unroll
    for (int ni = 0; ni < 4; ni++) {
      const int n = n0 + wn + ni * 16 + r16;
      const int nn = n - sec * 768;
      const int h = nn >> 6, d = nn & 63;
      const float bvs = bias[n];
      #pragma unroll
      for (int mi = 0; mi < 4; mi++) {
        #pragma unroll
        for (int reg = 0; reg < 4; reg++) {
          const int m = m0 + wm + mi * 16 + quad * 4 + reg;
          const int b = m >> 11, l = m & 2047;
          const float v = acc[mi][ni][reg] + bvs;
          dst[(((size_t)(b * Hc + h)) * Lc + l) * Dc + d] = (bf16_t)v;
        }
      }
    }
  }
}

__global__ __launch_bounds__(256) void k_gemm_out(
    const bf16_t* __restrict__ A, const bf16_t* __restrict__ Bt,
    const float* __restrict__ bias, float* __restrict__ out) {
  __shared__ bf16_t lA[128 * 32];
  __shared__ bf16_t lB[128 * 32];
  const int m0 = blockIdx.y * 128, n0 = blockIdx.x * 128;
  const int tid = threadIdx.x, wave = tid >> 6, lane = tid & 63;
  const int wm = (wave >> 1) * 64, wn = (wave & 1) * 64;
  const int quad = lane >> 4, r16 = lane & 15;
  floatx4 acc[4][4] = {};
  gemm_core(A, Bt, lA, lB, m0, n0, acc);
  #pragma unroll
  for (int ni = 0; ni < 4; ni++) {
    const int n = n0 + wn + ni * 16 + r16;
    const float bvs = bias[n];
    #pragma unroll
    for (int mi = 0; mi < 4; mi++) {
      #pragma unroll
      for (int reg = 0; reg < 4; reg++) {
        const int m = m0 + wm + mi * 16 + quad * 4 + reg;
        out[(size_t)m * Ec + n] = acc[mi][ni][reg] + bvs;
      }
    }
  }
}

// ---------------- q_sq / k_sq: ksq carries +eps and mask (sign sentinel) ----
__global__ __launch_bounds__(256) void k_sq(const bf16_t* __restrict__ Q,
                                            const bf16_t* __restrict__ K,
                                            const int* __restrict__ mask,
                                            float* __restrict__ qsq, float* __restrict__ ksq) {
  const int row = blockIdx.x * 256 + threadIdx.x;  // bh*2048 + l
  const bf16x8* q = (const bf16x8*)(Q + (size_t)row * 64);
  const bf16x8* k = (const bf16x8*)(K + (size_t)row * 64);
  float sq = 0.f, sk = 0.f;
  #pragma unroll
  for (int c = 0; c < 8; c++) {
    bf16x8 vq = q[c], vk = k[c];
    #pragma unroll
    for (int j = 0; j < 8; j++) {
      float a = (float)vq[j]; sq += a * a;
      float b = (float)vk[j]; sk += b * b;
    }
  }
  const int bh = row >> 11, l = row & 2047;
  const int b = bh / Hc;
  const int mk = mask[b * Lc + l];
  qsq[row] = sq;
  ksq[row] = (mk == 1) ? (sk + 1e-6f) : -1e30f;  // kss<0 => masked key
}

// ---------------- flash attention: LDS-staged, double-buffered, full-L ------
// grid = 768 (= 24 bh x 32 q-tiles = exact 3 blocks/CU). Block: 4 waves,
// 64 queries (wave = 16). Key tile = 64, nt = 32 tiles.
// S^T = K.Q^T scores; O^T = VT.P^T accum -> softmax state per-lane (q=r16).
__global__ __launch_bounds__(256) void k_attn(
    const bf16_t* __restrict__ Q, const bf16_t* __restrict__ K,
    const bf16_t* __restrict__ VT, const float* __restrict__ qsq,
    const float* __restrict__ ksq, bf16_t* __restrict__ AO) {
  __shared__ bf16_t lK[2][4096];   // 64 keys x 64 d, swizzled 16B chunks
  __shared__ bf16_t lV[2][4096];   // 64 d x 64 keys, swizzled 16B chunks
  __shared__ bf16_t lP[4][16 * 72];
  const int gid = blockIdx.x;
  const int bh = gid >> 5, qt = gid & 31;
  const int b = bh / Hc, h = bh - b * Hc;
  const int tid = threadIdx.x, wave = tid >> 6, lane = tid & 63;
  const int quad = lane >> 4, r16 = lane & 15;
  const int q0 = qt * 64 + wave * 16;
  const bf16_t* Qh = Q + ((size_t)bh * Lc) * Dc;
  const bf16_t* Kh = K + ((size_t)bh * Lc) * Dc;
  const bf16_t* VTh = VT + ((size_t)bh * Dc) * Lc;
  const float* qsqh = qsq + bh * Lc;
  const float* ksqh = ksq + bh * Lc;
  bf16_t* myP = &lP[wave][0];

  // staging geometry: chunk p = i*256 + wave*64 + lane covers row p>>3,
  // slot p&7 holding global chunk (p&7)^((p>>3)&7).
  const int p0 = wave * 64 + lane;
  const int srow = p0 >> 3;
  const int sj = (p0 & 7) ^ (srow & 7);
  const bf16_t* kg0 = Kh + (size_t)srow * 64 + sj * 8;
  const bf16_t* kg1 = kg0 + 32 * 64;
  const bf16_t* vg0 = VTh + (size_t)srow * Lc + sj * 8;
  const bf16_t* vg1 = vg0 + 32 * Lc;
  const int ld0 = wave * 64 * 8, ld1 = (256 + wave * 64) * 8;

  // fragment read offsets (swizzled slots), elements
  const int sl0 = ((quad ^ (r16 & 7)) * 8);
  const int sl1 = sl0 ^ 32;

  bf16x8 qf0 = *(const bf16x8*)(Qh + (size_t)(q0 + r16) * 64 + quad * 8);
  bf16x8 qf1 = *(const bf16x8*)(Qh + (size_t)(q0 + r16) * 64 + 32 + quad * 8);
  const float qs = qsqh[q0 + r16];
  float mi = -1e30f, li = 0.f;
  floatx4 of[4] = {};  // O^T: lane holds O^T[d=t4*16+quad*4+reg][q=r16]

  glds16(kg0, &lK[0][ld0]);
  glds16(kg1, &lK[0][ld1]);
  glds16(vg0, &lV[0][ld0]);
  glds16(vg1, &lV[0][ld1]);
  kg0 += 4096; kg1 += 4096; vg0 += 64; vg1 += 64;
  __syncthreads();

  const int nt = Lc / 64;  // 32
  for (int t = 0; t < nt; t++) {
    const int cur = t & 1;
    if (t + 1 < nt) {
      const int nxt = cur ^ 1;
      glds16(kg0, &lK[nxt][ld0]);
      glds16(kg1, &lK[nxt][ld1]);
      glds16(vg0, &lV[nxt][ld0]);
      glds16(vg1, &lV[nxt][ld1]);
      kg0 += 4096; kg1 += 4096; vg0 += 64; vg1 += 64;
    }
    const int kt = t * 64;
    float4 ks4[4];
    #pragma unroll
    for (int c = 0; c < 4; c++)
      ks4[c] = *(const float4*)(ksqh + kt + c * 16 + quad * 4);
    floatx4 dot[4];
    #pragma unroll
    for (int c = 0; c < 4; c++) {
      const int rbase = (c * 16 + r16) * 64;
      bf16x8 kf0 = *(const bf16x8*)(&lK[cur][rbase + sl0]);
      bf16x8 kf1 = *(const bf16x8*)(&lK[cur][rbase + sl1]);
      floatx4 a = {};
      a = __builtin_amdgcn_mfma_f32_16x16x32_bf16(kf0, qf0, a, 0, 0, 0);
      a = __builtin_amdgcn_mfma_f32_16x16x32_bf16(kf1, qf1, a, 0, 0, 0);
      dot[c] = a;
    }
    float sv[4][4];
    float rmax = -1e30f;
    #pragma unroll
    for (int c = 0; c < 4; c++) {
      #pragma unroll
      for (int reg = 0; reg < 4; reg++) {
        const float dd = dot[c][reg];
        const float kss = ((const float*)&ks4[c])[reg];  // +eps; <0 = masked
        const float den = qs + kss - 2.f * dd;
        float sc = dd * dd * __builtin_amdgcn_rcpf(den);
        sc = (kss < 0.f) ? -1e30f : sc;
        sv[c][reg] = sc;
        rmax = fmaxf(rmax, sc);
      }
    }
    rmax = fmaxf(rmax, __shfl_xor(rmax, 16));
    rmax = fmaxf(rmax, __shfl_xor(rmax, 32));
    const float mnew = fmaxf(mi, rmax);
    const float alpha = __expf(mi - mnew);
    float psum = 0.f;
    #pragma unroll
    for (int c = 0; c < 4; c++) {
      bf16x4 pk;
      #pragma unroll
      for (int reg = 0; reg < 4; reg++) {
        const float p = __expf(sv[c][reg] - mnew);
        psum += p;
        pk[reg] = (bf16_t)p;
      }
      *(bf16x4*)(myP + r16 * 72 + c * 16 + quad * 4) = pk;
    }
    psum += __shfl_xor(psum, 16);
    psum += __shfl_xor(psum, 32);
    li = li * alpha + psum;
    mi = mnew;
    #pragma unroll
    for (int t4 = 0; t4 < 4; t4++) {
      #pragma unroll
      for (int reg = 0; reg < 4; reg++) of[t4][reg] *= alpha;
    }
    bf16x8 pf0 = *(const bf16x8*)(myP + r16 * 72 + quad * 8);
    bf16x8 pf1 = *(const bf16x8*)(myP + r16 * 72 + 32 + quad * 8);
    #pragma unroll
    for (int t4 = 0; t4 < 4; t4++) {
      const int rbase = (t4 * 16 + r16) * 64;
      bf16x8 vf0 = *(const bf16x8*)(&lV[cur][rbase + sl0]);
      bf16x8 vf1 = *(const bf16x8*)(&lV[cur][rbase + sl1]);
      of[t4] = __builtin_amdgcn_mfma_f32_16x16x32_bf16(vf0, pf0, of[t4], 0, 0, 0);
      of[t4] = __builtin_amdgcn_mfma_f32_16x16x32_bf16(vf1, pf1, of[t4], 0, 0, 0);
    }
    __syncthreads();
  }
  // epilogue: normalize by this lane's own li (query r16) and write AO.
  const float inv = (li > 0.f) ? __builtin_amdgcn_rcpf(li) : 0.f;
  const int l = q0 + r16;
  bf16_t* aor = AO + ((size_t)(b * Lc + l)) * Ec + h * 64;
  #pragma unroll
  for (int t4 = 0; t4 < 4; t4++) {
    bf16x4 o;
    #pragma unroll
    for (int reg = 0; reg < 4; reg++) o[reg] = (bf16_t)(of[t4][reg] * inv);
    *(bf16x4*)(aor + t4 * 16 + quad * 4) = o;
  }
}

// ---------------- launch ----------------

extern "C" void kernel_launch(void* const* d_in, const int* in_sizes, int n_in,
                              void* d_out, int out_size, void* d_ws, size_t ws_size,
                              hipStream_t stream) {
  const float* x    = (const float*)d_in[0];
  const int*   mask = (const int*)d_in[1];
  const float* Wqkv = (const float*)d_in[2];
  const float* bqkv = (const float*)d_in[3];
  const float* Wout = (const float*)d_in[4];
  const float* bout = (const float*)d_in[5];
  float* out = (float*)d_out;

  auto al = [](size_t v) { return (v + 255) & ~(size_t)255; };
  char* ws = (char*)d_ws;
  size_t off = 0;
  auto carve = [&](size_t bytes) -> char* {
    char* p = ws + off;
    off += al(bytes);
    return p;
  };
  bf16_t* WoT = (bf16_t*)carve((size_t)Ec * Ec * 2);
  bf16_t* Qb  = (bf16_t*)carve((size_t)ROWSc * Dc * 2);
  bf16_t* Kb  = (bf16_t*)carve((size_t)ROWSc * Dc * 2);
  bf16_t* VTb = (bf16_t*)carve((size_t)ROWSc * Dc * 2);
  bf16_t* AOb = (bf16_t*)carve((size_t)Mc * Ec * 2);
  float*  qsq = (float*)carve((size_t)ROWSc * 4);
  float*  ksq = (float*)carve((size_t)ROWSc * 4);
  // phase-1 only (dead after k_gemm_qkv): xb, WqT
  bf16_t* xb  = (bf16_t*)carve((size_t)Mc * Ec * 2);
  bf16_t* WqT = (bf16_t*)carve((size_t)N3c * Ec * 2);
  (void)in_sizes; (void)n_in; (void)out_size; (void)ws_size;

  k_cvt<<<(Mc * Ec / 4 + 255) / 256, 256, 0, stream>>>(x, xb, Mc * Ec);
  k_tc<<<dim3(N3c / 32, Ec / 32), dim3(32, 8), 0, stream>>>(Wqkv, WqT, Ec, N3c);
  k_tc<<<dim3(Ec / 32, Ec / 32), dim3(32, 8), 0, stream>>>(Wout, WoT, Ec, Ec);
  k_gemm_qkv<<<dim3(N3c / 128, Mc / 128), 256, 0, stream>>>(xb, WqT, bqkv, Qb, Kb, VTb);
  k_sq<<<ROWSc / 256, 256, 0, stream>>>(Qb, Kb, mask, qsq, ksq);
  k_attn<<<ROWSc / 64, 256, 0, stream>>>(Qb, Kb, VTb, qsq, ksq, AOb);
  k_gemm_out<<<dim3(Ec / 128, Mc / 128), 256, 0, stream>>>(AOb, WoT, bout, out);
}

// Round 6
// 228.368 us; speedup vs baseline: 1.1095x; 1.1095x over previous
//
#include <hip/hip_runtime.h>
#include <hip/hip_bf16.h>
#include <cstdint>
#include <cstddef>

// YatAttention on MI355X (gfx950).
// B=2, L=2048, E=768, H=12, D=64. GEMMs in bf16 MFMA 16x16x32 (fp32 accum).
// R6: restore R4's split-K S=2 attention (1536 blocks -> 2x oversubscription
// of the 3-blocks/CU residency; R5's exact-fit 768-block grid lost 33% to
// zero-backfill load imbalance). Keep R5 wins: VT written directly by
// k_gemm_qkv (no k_vt), mask folded into ksq sign (no mask loads in loop).

typedef __bf16 bf16_t;
typedef __bf16 bf16x8 __attribute__((ext_vector_type(8)));
typedef __bf16 bf16x4 __attribute__((ext_vector_type(4)));
typedef float floatx4 __attribute__((ext_vector_type(4)));

#define DEVI static __device__ __forceinline__

#define Bc 2
#define Lc 2048
#define Ec 768
#define Hc 12
#define Dc 64
#define N3c 2304
#define Mc 4096
#define ROWSc (Bc * Hc * Lc)  // 49152

DEVI void glds16(const bf16_t* g, bf16_t* l) {
  __builtin_amdgcn_global_load_lds(
      (const __attribute__((address_space(1))) void*)g,
      (__attribute__((address_space(3))) void*)l, 16, 0, 0);
}

// ---------------- conversion kernels ----------------

__global__ __launch_bounds__(256) void k_cvt(const float* __restrict__ in,
                                             bf16_t* __restrict__ out, int n) {
  int i = (blockIdx.x * 256 + threadIdx.x) * 4;
  if (i >= n) return;
  float4 v = *(const float4*)(in + i);
  bf16x4 o;
  o[0] = (bf16_t)v.x; o[1] = (bf16_t)v.y; o[2] = (bf16_t)v.z; o[3] = (bf16_t)v.w;
  *(bf16x4*)(out + i) = o;
}

__global__ __launch_bounds__(256) void k_tc(const float* __restrict__ in,
                                            bf16_t* __restrict__ out, int R, int C) {
  __shared__ float tile[32][33];
  int c0 = blockIdx.x * 32, r0 = blockIdx.y * 32;
  int tx = threadIdx.x, ty = threadIdx.y;
  #pragma unroll
  for (int i = 0; i < 32; i += 8)
    tile[ty + i][tx] = in[(size_t)(r0 + ty + i) * C + c0 + tx];
  __syncthreads();
  #pragma unroll
  for (int i = 0; i < 32; i += 8)
    out[(size_t)(c0 + ty + i) * R + r0 + tx] = (bf16_t)tile[tx][ty + i];
}

// ---------------- GEMM core (m97 pattern) ----------------

DEVI void gemm_core(const bf16_t* __restrict__ A, const bf16_t* __restrict__ Bt,
                    bf16_t* lA, bf16_t* lB, int m0, int n0, floatx4 (&acc)[4][4]) {
  const int tid = threadIdx.x, wave = tid >> 6, lane = tid & 63;
  const int wm = (wave >> 1) * 64, wn = (wave & 1) * 64;
  const int lrow = lane >> 2, lseg = lane & 3;
  const int quad = lane >> 4, r16 = lane & 15;
  for (int kk = 0; kk < 768; kk += 32) {
    glds16(A  + (size_t)(m0 + wave * 32      + lrow) * 768 + kk + lseg * 8, lA + (wave * 32) * 32);
    glds16(A  + (size_t)(m0 + wave * 32 + 16 + lrow) * 768 + kk + lseg * 8, lA + (wave * 32 + 16) * 32);
    glds16(Bt + (size_t)(n0 + wave * 32      + lrow) * 768 + kk + lseg * 8, lB + (wave * 32) * 32);
    glds16(Bt + (size_t)(n0 + wave * 32 + 16 + lrow) * 768 + kk + lseg * 8, lB + (wave * 32 + 16) * 32);
    __syncthreads();
    bf16x8 af[4], bv[4];
    #pragma unroll
    for (int mi = 0; mi < 4; mi++)
      af[mi] = *(const bf16x8*)(lA + (wm + mi * 16 + r16) * 32 + quad * 8);
    #pragma unroll
    for (int ni = 0; ni < 4; ni++)
      bv[ni] = *(const bf16x8*)(lB + (wn + ni * 16 + r16) * 32 + quad * 8);
    #pragma unroll
    for (int mi = 0; mi < 4; mi++)
      #pragma unroll
      for (int ni = 0; ni < 4; ni++)
        acc[mi][ni] = __builtin_amdgcn_mfma_f32_16x16x32_bf16(af[mi], bv[ni], acc[mi][ni], 0, 0, 0);
    __syncthreads();
  }
}

// QKV GEMM. Q,K sections -> (B,H,L,D); V section -> VT (B,H,D,L) directly.
__global__ __launch_bounds__(256) void k_gemm_qkv(
    const bf16_t* __restrict__ A, const bf16_t* __restrict__ Bt,
    const float* __restrict__ bias,
    bf16_t* __restrict__ Qo, bf16_t* __restrict__ Ko, bf16_t* __restrict__ VTo) {
  __shared__ bf16_t lA[128 * 32];
  __shared__ bf16_t lB[128 * 32];
  const int m0 = blockIdx.y * 128, n0 = blockIdx.x * 128;
  const int tid = threadIdx.x, wave = tid >> 6, lane = tid & 63;
  const int wm = (wave >> 1) * 64, wn = (wave & 1) * 64;
  const int quad = lane >> 4, r16 = lane & 15;
  floatx4 acc[4][4] = {};
  gemm_core(A, Bt, lA, lB, m0, n0, acc);

  const int sec = n0 / 768;  // block-uniform: 6 full 128-tiles per section
  if (sec == 2) {
    #pragma unroll
    for (int ni = 0; ni < 4; ni++) {
      const int n = n0 + wn + ni * 16 + r16;
      const int nn = n - 1536;
      const int h = nn >> 6, d = nn & 63;
      const float bvs = bias[n];
      #pragma unroll
      for (int mi = 0; mi < 4; mi++) {
        const int m = m0 + wm + mi * 16 + quad * 4;
        const int b = m >> 11, l = m & 2047;
        bf16x4 o;
        #pragma unroll
        for (int reg = 0; reg < 4; reg++) o[reg] = (bf16_t)(acc[mi][ni][reg] + bvs);
        *(bf16x4*)(VTo + ((size_t)(b * Hc + h) * Dc + d) * Lc + l) = o;
      }
    }
  } else {
    bf16_t* dst = (sec == 0) ? Qo : Ko;
    #pragma unroll
    for (int ni = 0; ni < 4; ni++) {
      const int n = n0 + wn + ni * 16 + r16;
      const int nn = n - sec * 768;
      const int h = nn >> 6, d = nn & 63;
      const float bvs = bias[n];
      #pragma unroll
      for (int mi = 0; mi < 4; mi++) {
        #pragma unroll
        for (int reg = 0; reg < 4; reg++) {
          const int m = m0 + wm + mi * 16 + quad * 4 + reg;
          const int b = m >> 11, l = m & 2047;
          const float v = acc[mi][ni][reg] + bvs;
          dst[(((size_t)(b * Hc + h)) * Lc + l) * Dc + d] = (bf16_t)v;
        }
      }
    }
  }
}

__global__ __launch_bounds__(256) void k_gemm_out(
    const bf16_t* __restrict__ A, const bf16_t* __restrict__ Bt,
    const float* __restrict__ bias, float* __restrict__ out) {
  __shared__ bf16_t lA[128 * 32];
  __shared__ bf16_t lB[128 * 32];
  const int m0 = blockIdx.y * 128, n0 = blockIdx.x * 128;
  const int tid = threadIdx.x, wave = tid >> 6, lane = tid & 63;
  const int wm = (wave >> 1) * 64, wn = (wave & 1) * 64;
  const int quad = lane >> 4, r16 = lane & 15;
  floatx4 acc[4][4] = {};
  gemm_core(A, Bt, lA, lB, m0, n0, acc);
  #pragma unroll
  for (int ni = 0; ni < 4; ni++) {
    const int n = n0 + wn + ni * 16 + r16;
    const float bvs = bias[n];
    #pragma unroll
    for (int mi = 0; mi < 4; mi++) {
      #pragma unroll
      for (int reg = 0; reg < 4; reg++) {
        const int m = m0 + wm + mi * 16 + quad * 4 + reg;
        out[(size_t)m * Ec + n] = acc[mi][ni][reg] + bvs;
      }
    }
  }
}

// ---------------- q_sq / k_sq: ksq carries +eps and mask (sign sentinel) ----
__global__ __launch_bounds__(256) void k_sq(const bf16_t* __restrict__ Q,
                                            const bf16_t* __restrict__ K,
                                            const int* __restrict__ mask,
                                            float* __restrict__ qsq, float* __restrict__ ksq) {
  const int row = blockIdx.x * 256 + threadIdx.x;  // bh*2048 + l
  const bf16x8* q = (const bf16x8*)(Q + (size_t)row * 64);
  const bf16x8* k = (const bf16x8*)(K + (size_t)row * 64);
  float sq = 0.f, sk = 0.f;
  #pragma unroll
  for (int c = 0; c < 8; c++) {
    bf16x8 vq = q[c], vk = k[c];
    #pragma unroll
    for (int j = 0; j < 8; j++) {
      float a = (float)vq[j]; sq += a * a;
      float b = (float)vk[j]; sk += b * b;
    }
  }
  const int bh = row >> 11, l = row & 2047;
  const int b = bh / Hc;
  const int mk = mask[b * Lc + l];
  qsq[row] = sq;
  ksq[row] = (mk == 1) ? (sk + 1e-6f) : -1e30f;  // kss<0 => masked key
}

// ---------------- flash attention: LDS-staged, double-buffered, split-K -----
// grid = (768, S). Block: 4 waves, 64 queries (wave = 16). Key tile = 64.
// S^T = K.Q^T scores; O^T = VT.P^T accum -> softmax state per-lane (q=r16).
__global__ __launch_bounds__(256) void k_attn(
    const bf16_t* __restrict__ Q, const bf16_t* __restrict__ K,
    const bf16_t* __restrict__ VT, const float* __restrict__ qsq,
    const float* __restrict__ ksq,
    float* __restrict__ Op, float* __restrict__ Mp, float* __restrict__ Lp,
    int nS) {
  __shared__ bf16_t lK[2][4096];   // 64 keys x 64 d, swizzled 16B chunks
  __shared__ bf16_t lV[2][4096];   // 64 d x 64 keys, swizzled 16B chunks
  __shared__ bf16_t lP[4][16 * 72];
  const int gid = blockIdx.x;
  const int s = blockIdx.y;
  const int bh = gid >> 5, qt = gid & 31;
  const int tid = threadIdx.x, wave = tid >> 6, lane = tid & 63;
  const int quad = lane >> 4, r16 = lane & 15;
  const int q0 = qt * 64 + wave * 16;
  const bf16_t* Qh = Q + ((size_t)bh * Lc) * Dc;
  const bf16_t* Kh = K + ((size_t)bh * Lc) * Dc;
  const bf16_t* VTh = VT + ((size_t)bh * Dc) * Lc;
  const float* qsqh = qsq + bh * Lc;
  const float* ksqh = ksq + bh * Lc;
  bf16_t* myP = &lP[wave][0];

  const int kt_lo = (32 * s) / nS * 64;
  const int kt_hi = (32 * (s + 1)) / nS * 64;
  const int nt = (kt_hi - kt_lo) >> 6;

  // staging geometry: chunk p = i*256 + wave*64 + lane covers row p>>3,
  // slot p&7 holding global chunk (p&7)^((p>>3)&7).
  const int p0 = wave * 64 + lane;
  const int srow = p0 >> 3;
  const int sj = (p0 & 7) ^ (srow & 7);
  const bf16_t* kg0 = Kh + (size_t)(kt_lo + srow) * 64 + sj * 8;
  const bf16_t* kg1 = kg0 + 32 * 64;
  const bf16_t* vg0 = VTh + (size_t)srow * Lc + kt_lo + sj * 8;
  const bf16_t* vg1 = vg0 + 32 * Lc;
  const int ld0 = wave * 64 * 8, ld1 = (256 + wave * 64) * 8;

  // fragment read offsets (swizzled slots), elements
  const int sl0 = ((quad ^ (r16 & 7)) * 8);
  const int sl1 = sl0 ^ 32;

  bf16x8 qf0 = *(const bf16x8*)(Qh + (size_t)(q0 + r16) * 64 + quad * 8);
  bf16x8 qf1 = *(const bf16x8*)(Qh + (size_t)(q0 + r16) * 64 + 32 + quad * 8);
  const float qs = qsqh[q0 + r16];
  float mi = -1e30f, li = 0.f;
  floatx4 of[4] = {};  // O^T: lane holds O^T[d=t4*16+quad*4+reg][q=r16]

  glds16(kg0, &lK[0][ld0]);
  glds16(kg1, &lK[0][ld1]);
  glds16(vg0, &lV[0][ld0]);
  glds16(vg1, &lV[0][ld1]);
  kg0 += 4096; kg1 += 4096; vg0 += 64; vg1 += 64;
  __syncthreads();

  for (int t = 0; t < nt; t++) {
    const int cur = t & 1;
    if (t + 1 < nt) {
      const int nxt = cur ^ 1;
      glds16(kg0, &lK[nxt][ld0]);
      glds16(kg1, &lK[nxt][ld1]);
      glds16(vg0, &lV[nxt][ld0]);
      glds16(vg1, &lV[nxt][ld1]);
      kg0 += 4096; kg1 += 4096; vg0 += 64; vg1 += 64;
    }
    const int kt = kt_lo + t * 64;
    float4 ks4[4];
    #pragma unroll
    for (int c = 0; c < 4; c++)
      ks4[c] = *(const float4*)(ksqh + kt + c * 16 + quad * 4);
    floatx4 dot[4];
    #pragma unroll
    for (int c = 0; c < 4; c++) {
      const int rbase = (c * 16 + r16) * 64;
      bf16x8 kf0 = *(const bf16x8*)(&lK[cur][rbase + sl0]);
      bf16x8 kf1 = *(const bf16x8*)(&lK[cur][rbase + sl1]);
      floatx4 a = {};
      a = __builtin_amdgcn_mfma_f32_16x16x32_bf16(kf0, qf0, a, 0, 0, 0);
      a = __builtin_amdgcn_mfma_f32_16x16x32_bf16(kf1, qf1, a, 0, 0, 0);
      dot[c] = a;
    }
    float sv[4][4];
    float rmax = -1e30f;
    #pragma unroll
    for (int c = 0; c < 4; c++) {
      #pragma unroll
      for (int reg = 0; reg < 4; reg++) {
        const float dd = dot[c][reg];
        const float kss = ((const float*)&ks4[c])[reg];  // +eps; <0 = masked
        const float den = qs + kss - 2.f * dd;
        float sc = dd * dd * __builtin_amdgcn_rcpf(den);
        sc = (kss < 0.f) ? -1e30f : sc;
        sv[c][reg] = sc;
        rmax = fmaxf(rmax, sc);
      }
    }
    rmax = fmaxf(rmax, __shfl_xor(rmax, 16));
    rmax = fmaxf(rmax, __shfl_xor(rmax, 32));
    const float mnew = fmaxf(mi, rmax);
    const float alpha = __expf(mi - mnew);
    float psum = 0.f;
    #pragma unroll
    for (int c = 0; c < 4; c++) {
      bf16x4 pk;
      #pragma unroll
      for (int reg = 0; reg < 4; reg++) {
        const float p = __expf(sv[c][reg] - mnew);
        psum += p;
        pk[reg] = (bf16_t)p;
      }
      *(bf16x4*)(myP + r16 * 72 + c * 16 + quad * 4) = pk;
    }
    psum += __shfl_xor(psum, 16);
    psum += __shfl_xor(psum, 32);
    li = li * alpha + psum;
    mi = mnew;
    #pragma unroll
    for (int t4 = 0; t4 < 4; t4++) {
      #pragma unroll
      for (int reg = 0; reg < 4; reg++) of[t4][reg] *= alpha;
    }
    bf16x8 pf0 = *(const bf16x8*)(myP + r16 * 72 + quad * 8);
    bf16x8 pf1 = *(const bf16x8*)(myP + r16 * 72 + 32 + quad * 8);
    #pragma unroll
    for (int t4 = 0; t4 < 4; t4++) {
      const int rbase = (t4 * 16 + r16) * 64;
      bf16x8 vf0 = *(const bf16x8*)(&lV[cur][rbase + sl0]);
      bf16x8 vf1 = *(const bf16x8*)(&lV[cur][rbase + sl1]);
      of[t4] = __builtin_amdgcn_mfma_f32_16x16x32_bf16(vf0, pf0, of[t4], 0, 0, 0);
      of[t4] = __builtin_amdgcn_mfma_f32_16x16x32_bf16(vf1, pf1, of[t4], 0, 0, 0);
    }
    __syncthreads();
  }
  // epilogue: lane owns O^T[d=t4*16+quad*4..+3][q=r16]; write fp32 partials.
  const size_t idx = (size_t)s * ROWSc + (size_t)bh * Lc + q0 + r16;
  #pragma unroll
  for (int t4 = 0; t4 < 4; t4++)
    *(float4*)(Op + idx * 64 + t4 * 16 + quad * 4) =
        make_float4(of[t4][0], of[t4][1], of[t4][2], of[t4][3]);
  if (lane < 16) { Mp[idx] = mi; Lp[idx] = li; }
}

// ---------------- merge partials -> AO (bf16, (B,L,E)) ----------------
__global__ __launch_bounds__(256) void k_merge(
    const float* __restrict__ Op, const float* __restrict__ Mp,
    const float* __restrict__ Lp, bf16_t* __restrict__ AO, int nS) {
  const int t = blockIdx.x * 256 + threadIdx.x;
  const int row = t >> 4, dc = (t & 15) * 4;
  float mmax = -1e30f;
  for (int s = 0; s < nS; s++) mmax = fmaxf(mmax, Mp[(size_t)s * ROWSc + row]);
  float L = 0.f;
  float o0 = 0.f, o1 = 0.f, o2 = 0.f, o3 = 0.f;
  for (int s = 0; s < nS; s++) {
    const size_t idx = (size_t)s * ROWSc + row;
    const float w = __expf(Mp[idx] - mmax);
    L += w * Lp[idx];
    const float4 v = *(const float4*)(Op + idx * 64 + dc);
    o0 += w * v.x; o1 += w * v.y; o2 += w * v.z; o3 += w * v.w;
  }
  const float inv = (L > 0.f) ? __builtin_amdgcn_rcpf(L) : 0.f;
  const int bh = row >> 11, l = row & 2047;
  const int b = bh / Hc, h = bh - b * Hc;
  bf16x4 o;
  o[0] = (bf16_t)(o0 * inv); o[1] = (bf16_t)(o1 * inv);
  o[2] = (bf16_t)(o2 * inv); o[3] = (bf16_t)(o3 * inv);
  *(bf16x4*)(AO + ((size_t)(b * Lc + l)) * Ec + h * 64 + dc) = o;
}

// ---------------- launch ----------------

extern "C" void kernel_launch(void* const* d_in, const int* in_sizes, int n_in,
                              void* d_out, int out_size, void* d_ws, size_t ws_size,
                              hipStream_t stream) {
  const float* x    = (const float*)d_in[0];
  const int*   mask = (const int*)d_in[1];
  const float* Wqkv = (const float*)d_in[2];
  const float* bqkv = (const float*)d_in[3];
  const float* Wout = (const float*)d_in[4];
  const float* bout = (const float*)d_in[5];
  float* out = (float*)d_out;

  auto al = [](size_t v) { return (v + 255) & ~(size_t)255; };
  char* ws = (char*)d_ws;
  size_t off = 0;
  auto carve = [&](size_t bytes) -> char* {
    char* p = ws + off;
    off += al(bytes);
    return p;
  };
  // persistent across phases
  bf16_t* WoT = (bf16_t*)carve((size_t)Ec * Ec * 2);
  bf16_t* Qb  = (bf16_t*)carve((size_t)ROWSc * Dc * 2);
  bf16_t* Kb  = (bf16_t*)carve((size_t)ROWSc * Dc * 2);
  bf16_t* VTb = (bf16_t*)carve((size_t)ROWSc * Dc * 2);
  bf16_t* AOb = (bf16_t*)carve((size_t)Mc * Ec * 2);
  float*  qsq = (float*)carve((size_t)ROWSc * 4);
  float*  ksq = (float*)carve((size_t)ROWSc * 4);
  const size_t uni = off;
  // phase-1 view (dead after k_gemm_qkv): xb, WqT
  bf16_t* xb  = (bf16_t*)(ws + uni);
  bf16_t* WqT = (bf16_t*)(ws + uni + al((size_t)Mc * Ec * 2));
  const size_t ph1 = al((size_t)Mc * Ec * 2) + al((size_t)N3c * Ec * 2);
  // phase-2 view (k_attn -> k_merge): Op, Mp, Lp
  auto ph2 = [&](int S) {
    return al((size_t)S * ROWSc * Dc * 4) + 2 * al((size_t)S * ROWSc * 4);
  };
  int S = 1;
  {
    size_t need = uni + (ph1 > ph2(2) ? ph1 : ph2(2));
    if (need <= ws_size) S = 2;
  }
  float* Op = (float*)(ws + uni);
  float* Mp = (float*)(ws + uni + al((size_t)S * ROWSc * Dc * 4));
  float* Lp = (float*)(ws + uni + al((size_t)S * ROWSc * Dc * 4) + al((size_t)S * ROWSc * 4));
  (void)in_sizes; (void)n_in; (void)out_size;

  k_cvt<<<(Mc * Ec / 4 + 255) / 256, 256, 0, stream>>>(x, xb, Mc * Ec);
  k_tc<<<dim3(N3c / 32, Ec / 32), dim3(32, 8), 0, stream>>>(Wqkv, WqT, Ec, N3c);
  k_tc<<<dim3(Ec / 32, Ec / 32), dim3(32, 8), 0, stream>>>(Wout, WoT, Ec, Ec);
  k_gemm_qkv<<<dim3(N3c / 128, Mc / 128), 256, 0, stream>>>(xb, WqT, bqkv, Qb, Kb, VTb);
  k_sq<<<ROWSc / 256, 256, 0, stream>>>(Qb, Kb, mask, qsq, ksq);
  k_attn<<<dim3(ROWSc / 64, S), 256, 0, stream>>>(Qb, Kb, VTb, qsq, ksq, Op, Mp, Lp, S);
  k_merge<<<ROWSc * 16 / 256, 256, 0, stream>>>(Op, Mp, Lp, AOb, S);
  k_gemm_out<<<dim3(Ec / 128, Mc / 128), 256, 0, stream>>>(AOb, WoT, bout, out);
}

// Round 7
// 223.440 us; speedup vs baseline: 1.1339x; 1.0221x over previous
//
#include <hip/hip_runtime.h>
#include <hip/hip_bf16.h>
#include <cstdint>
#include <cstddef>

// YatAttention on MI355X (gfx950).
// B=2, L=2048, E=768, H=12, D=64. GEMMs in bf16 MFMA 16x16x32 (fp32 accum).
// R7: k_attn occupancy 3->6 blocks/CU (single-buffered 25.6KB LDS, S=4 for
// >=2 residency generations, fp16 O-partials keep traffic at R6 level),
// floatx4/pk-math transform, ballot-skipped alpha rescale. Prep kernels
// fused (8->6 launches). Grid-skew rule: grid >= 2x residency capacity.

typedef __bf16 bf16_t;
typedef __bf16 bf16x8 __attribute__((ext_vector_type(8)));
typedef __bf16 bf16x4 __attribute__((ext_vector_type(4)));
typedef float floatx4 __attribute__((ext_vector_type(4)));
typedef _Float16 half_t;
typedef _Float16 half4 __attribute__((ext_vector_type(4)));

#define DEVI static __device__ __forceinline__

#define Bc 2
#define Lc 2048
#define Ec 768
#define Hc 12
#define Dc 64
#define N3c 2304
#define Mc 4096
#define ROWSc (Bc * Hc * Lc)  // 49152

DEVI void glds16(const bf16_t* g, bf16_t* l) {
  __builtin_amdgcn_global_load_lds(
      (const __attribute__((address_space(1))) void*)g,
      (__attribute__((address_space(3))) void*)l, 16, 0, 0);
}

// ---------------- fused prep: x->bf16, Wqkv^T, Wout^T ----------------
#define NBCVT 3072
#define NBTC1 1728  // (2304/32) x (768/32)
#define NBTC2 576   // (768/32)  x (768/32)

__global__ __launch_bounds__(256) void k_prep(
    const float* __restrict__ x, bf16_t* __restrict__ xb,
    const float* __restrict__ Wqkv, bf16_t* __restrict__ WqT,
    const float* __restrict__ Wout, bf16_t* __restrict__ WoT) {
  const int bid = blockIdx.x, tid = threadIdx.x;
  if (bid < NBCVT) {
    const int i = (bid * 256 + tid) * 4;
    float4 v = *(const float4*)(x + i);
    bf16x4 o;
    o[0] = (bf16_t)v.x; o[1] = (bf16_t)v.y; o[2] = (bf16_t)v.z; o[3] = (bf16_t)v.w;
    *(bf16x4*)(xb + i) = o;
    return;
  }
  __shared__ float tile[32][33];
  const float* in; bf16_t* out; int C, bx, by;
  if (bid < NBCVT + NBTC1) {
    const int r = bid - NBCVT;
    in = Wqkv; out = WqT; C = N3c; bx = r % 72; by = r / 72;
  } else {
    const int r = bid - NBCVT - NBTC1;
    in = Wout; out = WoT; C = Ec; bx = r % 24; by = r / 24;
  }
  const int R = Ec;
  const int c0 = bx * 32, r0 = by * 32;
  const int tx = tid & 31, ty = tid >> 5;
  #pragma unroll
  for (int i = 0; i < 32; i += 8)
    tile[ty + i][tx] = in[(size_t)(r0 + ty + i) * C + c0 + tx];
  __syncthreads();
  #pragma unroll
  for (int i = 0; i < 32; i += 8)
    out[(size_t)(c0 + ty + i) * R + r0 + tx] = (bf16_t)tile[tx][ty + i];
}

// ---------------- GEMM core (m97 pattern) ----------------

DEVI void gemm_core(const bf16_t* __restrict__ A, const bf16_t* __restrict__ Bt,
                    bf16_t* lA, bf16_t* lB, int m0, int n0, floatx4 (&acc)[4][4]) {
  const int tid = threadIdx.x, wave = tid >> 6, lane = tid & 63;
  const int wm = (wave >> 1) * 64, wn = (wave & 1) * 64;
  const int lrow = lane >> 2, lseg = lane & 3;
  const int quad = lane >> 4, r16 = lane & 15;
  for (int kk = 0; kk < 768; kk += 32) {
    glds16(A  + (size_t)(m0 + wave * 32      + lrow) * 768 + kk + lseg * 8, lA + (wave * 32) * 32);
    glds16(A  + (size_t)(m0 + wave * 32 + 16 + lrow) * 768 + kk + lseg * 8, lA + (wave * 32 + 16) * 32);
    glds16(Bt + (size_t)(n0 + wave * 32      + lrow) * 768 + kk + lseg * 8, lB + (wave * 32) * 32);
    glds16(Bt + (size_t)(n0 + wave * 32 + 16 + lrow) * 768 + kk + lseg * 8, lB + (wave * 32 + 16) * 32);
    __syncthreads();
    bf16x8 af[4], bv[4];
    #pragma unroll
    for (int mi = 0; mi < 4; mi++)
      af[mi] = *(const bf16x8*)(lA + (wm + mi * 16 + r16) * 32 + quad * 8);
    #pragma unroll
    for (int ni = 0; ni < 4; ni++)
      bv[ni] = *(const bf16x8*)(lB + (wn + ni * 16 + r16) * 32 + quad * 8);
    #pragma unroll
    for (int mi = 0; mi < 4; mi++)
      #pragma unroll
      for (int ni = 0; ni < 4; ni++)
        acc[mi][ni] = __builtin_amdgcn_mfma_f32_16x16x32_bf16(af[mi], bv[ni], acc[mi][ni], 0, 0, 0);
    __syncthreads();
  }
}

// QKV GEMM. Q,K sections -> (B,H,L,D); V section -> VT (B,H,D,L) directly.
__global__ __launch_bounds__(256) void k_gemm_qkv(
    const bf16_t* __restrict__ A, const bf16_t* __restrict__ Bt,
    const float* __restrict__ bias,
    bf16_t* __restrict__ Qo, bf16_t* __restrict__ Ko, bf16_t* __restrict__ VTo) {
  __shared__ bf16_t lA[128 * 32];
  __shared__ bf16_t lB[128 * 32];
  const int m0 = blockIdx.y * 128, n0 = blockIdx.x * 128;
  const int tid = threadIdx.x, wave = tid >> 6, lane = tid & 63;
  const int wm = (wave >> 1) * 64, wn = (wave & 1) * 64;
  const int quad = lane >> 4, r16 = lane & 15;
  floatx4 acc[4][4] = {};
  gemm_core(A, Bt, lA, lB, m0, n0, acc);

  const int sec = n0 / 768;  // block-uniform: 6 full 128-tiles per section
  if (sec == 2) {
    #pragma unroll
    for (int ni = 0; ni < 4; ni++) {
      const int n = n0 + wn + ni * 16 + r16;
      const int nn = n - 1536;
      const int h = nn >> 6, d = nn & 63;
      const float bvs = bias[n];
      #pragma unroll
      for (int mi = 0; mi < 4; mi++) {
        const int m = m0 + wm + mi * 16 + quad * 4;
        const int b = m >> 11, l = m & 2047;
        bf16x4 o;
        #pragma unroll
        for (int reg = 0; reg < 4; reg++) o[reg] = (bf16_t)(acc[mi][ni][reg] + bvs);
        *(bf16x4*)(VTo + ((size_t)(b * Hc + h) * Dc + d) * Lc + l) = o;
      }
    }
  } else {
    bf16_t* dst = (sec == 0) ? Qo : Ko;
    #pragma unroll
    for (int ni = 0; ni < 4; ni++) {
      const int n = n0 + wn + ni * 16 + r16;
      const int nn = n - sec * 768;
      const int h = nn >> 6, d = nn & 63;
      const float bvs = bias[n];
      #pragma unroll
      for (int mi = 0; mi < 4; mi++) {
        #pragma unroll
        for (int reg = 0; reg < 4; reg++) {
          const int m = m0 + wm + mi * 16 + quad * 4 + reg;
          const int b = m >> 11, l = m & 2047;
          const float v = acc[mi][ni][reg] + bvs;
          dst[(((size_t)(b * Hc + h)) * Lc + l) * Dc + d] = (bf16_t)v;
        }
      }
    }
  }
}

__global__ __launch_bounds__(256) void k_gemm_out(
    const bf16_t* __restrict__ A, const bf16_t* __restrict__ Bt,
    const float* __restrict__ bias, float* __restrict__ out) {
  __shared__ bf16_t lA[128 * 32];
  __shared__ bf16_t lB[128 * 32];
  const int m0 = blockIdx.y * 128, n0 = blockIdx.x * 128;
  const int tid = threadIdx.x, wave = tid >> 6, lane = tid & 63;
  const int wm = (wave >> 1) * 64, wn = (wave & 1) * 64;
  const int quad = lane >> 4, r16 = lane & 15;
  floatx4 acc[4][4] = {};
  gemm_core(A, Bt, lA, lB, m0, n0, acc);
  #pragma unroll
  for (int ni = 0; ni < 4; ni++) {
    const int n = n0 + wn + ni * 16 + r16;
    const float bvs = bias[n];
    #pragma unroll
    for (int mi = 0; mi < 4; mi++) {
      #pragma unroll
      for (int reg = 0; reg < 4; reg++) {
        const int m = m0 + wm + mi * 16 + quad * 4 + reg;
        out[(size_t)m * Ec + n] = acc[mi][ni][reg] + bvs;
      }
    }
  }
}

// ---------------- q_sq / k_sq: ksq carries +eps and mask (sign sentinel) ----
__global__ __launch_bounds__(256) void k_sq(const bf16_t* __restrict__ Q,
                                            const bf16_t* __restrict__ K,
                                            const int* __restrict__ mask,
                                            float* __restrict__ qsq, float* __restrict__ ksq) {
  const int row = blockIdx.x * 256 + threadIdx.x;  // bh*2048 + l
  const bf16x8* q = (const bf16x8*)(Q + (size_t)row * 64);
  const bf16x8* k = (const bf16x8*)(K + (size_t)row * 64);
  float sq = 0.f, sk = 0.f;
  #pragma unroll
  for (int c = 0; c < 8; c++) {
    bf16x8 vq = q[c], vk = k[c];
    #pragma unroll
    for (int j = 0; j < 8; j++) {
      float a = (float)vq[j]; sq += a * a;
      float b = (float)vk[j]; sk += b * b;
    }
  }
  const int bh = row >> 11, l = row & 2047;
  const int b = bh / Hc;
  const int mk = mask[b * Lc + l];
  qsq[row] = sq;
  ksq[row] = (mk == 1) ? (sk + 1e-6f) : -1e30f;  // qs+kss < 0 => masked key
}

// ---------------- flash attention: single-buffered LDS, 6 blocks/CU --------
// grid = (768, S=4). Block: 4 waves, 64 queries (wave = 16). Key tile = 64.
// LDS = 8K (K) + 8K (V) + 9K (P) = 25.6KB -> 6 blocks/CU = 24 waves/CU.
// S^T = K.Q^T scores; O^T = VT.P^T accum -> softmax state per-lane (q=r16).
__global__ __launch_bounds__(256, 6) void k_attn(
    const bf16_t* __restrict__ Q, const bf16_t* __restrict__ K,
    const bf16_t* __restrict__ VT, const float* __restrict__ qsq,
    const float* __restrict__ ksq,
    half_t* __restrict__ Op, float* __restrict__ Mp, float* __restrict__ Lp,
    int nS) {
  __shared__ bf16_t lK[4096];   // 64 keys x 64 d, swizzled 16B chunks
  __shared__ bf16_t lV[4096];   // 64 d x 64 keys, swizzled 16B chunks
  __shared__ bf16_t lP[4][16 * 72];
  const int gid = blockIdx.x;
  const int s = blockIdx.y;
  const int bh = gid >> 5, qt = gid & 31;
  const int tid = threadIdx.x, wave = tid >> 6, lane = tid & 63;
  const int quad = lane >> 4, r16 = lane & 15;
  const int q0 = qt * 64 + wave * 16;
  const bf16_t* Qh = Q + ((size_t)bh * Lc) * Dc;
  const bf16_t* Kh = K + ((size_t)bh * Lc) * Dc;
  const bf16_t* VTh = VT + ((size_t)bh * Dc) * Lc;
  const float* qsqh = qsq + bh * Lc;
  const float* ksqh = ksq + bh * Lc;
  bf16_t* myP = &lP[wave][0];

  const int kt_lo = (32 * s) / nS * 64;
  const int kt_hi = (32 * (s + 1)) / nS * 64;
  const int nt = (kt_hi - kt_lo) >> 6;

  // staging geometry: chunk p = i*256 + wave*64 + lane covers row p>>3,
  // slot p&7 holding global chunk (p&7)^((p>>3)&7).
  const int p0 = wave * 64 + lane;
  const int srow = p0 >> 3;
  const int sj = (p0 & 7) ^ (srow & 7);
  const bf16_t* kg0 = Kh + (size_t)(kt_lo + srow) * 64 + sj * 8;
  const bf16_t* kg1 = kg0 + 32 * 64;
  const bf16_t* vg0 = VTh + (size_t)srow * Lc + kt_lo + sj * 8;
  const bf16_t* vg1 = vg0 + 32 * Lc;
  const int ld0 = wave * 64 * 8, ld1 = (256 + wave * 64) * 8;

  // fragment read offsets (swizzled slots), elements
  const int sl0 = ((quad ^ (r16 & 7)) * 8);
  const int sl1 = sl0 ^ 32;

  bf16x8 qf0 = *(const bf16x8*)(Qh + (size_t)(q0 + r16) * 64 + quad * 8);
  bf16x8 qf1 = *(const bf16x8*)(Qh + (size_t)(q0 + r16) * 64 + 32 + quad * 8);
  const float qs = qsqh[q0 + r16];
  float mi = -1e30f, li = 0.f;
  floatx4 of[4] = {};  // O^T: lane holds O^T[d=t4*16+quad*4+reg][q=r16]

  for (int t = 0; t < nt; t++) {
    const int kt = kt_lo + t * 64;
    // qs+kss (sign<0 = masked) for this lane's 16 keys, vector form
    floatx4 qsk[4];
    #pragma unroll
    for (int c = 0; c < 4; c++)
      qsk[c] = qs + *(const floatx4*)(ksqh + kt + c * 16 + quad * 4);
    __syncthreads();  // all waves done reading lK/lV of previous tile
    glds16(kg0, &lK[ld0]);
    glds16(kg1, &lK[ld1]);
    glds16(vg0, &lV[ld0]);
    glds16(vg1, &lV[ld1]);
    kg0 += 4096; kg1 += 4096; vg0 += 64; vg1 += 64;
    __syncthreads();  // staging complete (vmcnt drained at barrier)

    floatx4 dot[4];
    #pragma unroll
    for (int c = 0; c < 4; c++) {
      const int rbase = (c * 16 + r16) * 64;
      bf16x8 kf0 = *(const bf16x8*)(&lK[rbase + sl0]);
      bf16x8 kf1 = *(const bf16x8*)(&lK[rbase + sl1]);
      floatx4 a = {};
      a = __builtin_amdgcn_mfma_f32_16x16x32_bf16(kf0, qf0, a, 0, 0, 0);
      a = __builtin_amdgcn_mfma_f32_16x16x32_bf16(kf1, qf1, a, 0, 0, 0);
      dot[c] = a;
    }
    // transform, vectorized (pk math): sc = d^2 / (qsk - 2d), masked by sign
    floatx4 sv4[4];
    floatx4 mx = {-1e30f, -1e30f, -1e30f, -1e30f};
    #pragma unroll
    for (int c = 0; c < 4; c++) {
      const floatx4 den = qsk[c] - 2.f * dot[c];
      const floatx4 num = dot[c] * dot[c];
      floatx4 sc;
      #pragma unroll
      for (int e = 0; e < 4; e++) {
        float v = num[e] * __builtin_amdgcn_rcpf(den[e]);
        sc[e] = (qsk[c][e] < 0.f) ? -1e30f : v;
        mx[e] = fmaxf(mx[e], sc[e]);
      }
      sv4[c] = sc;
    }
    float rmax = fmaxf(fmaxf(mx[0], mx[1]), fmaxf(mx[2], mx[3]));
    rmax = fmaxf(rmax, __shfl_xor(rmax, 16));
    rmax = fmaxf(rmax, __shfl_xor(rmax, 32));
    const float mnew = fmaxf(mi, rmax);
    if (__ballot(rmax > mi) != 0ull) {  // some query's max moved: rescale
      const float alpha = __expf(mi - mnew);
      #pragma unroll
      for (int t4 = 0; t4 < 4; t4++) {
        #pragma unroll
        for (int reg = 0; reg < 4; reg++) of[t4][reg] *= alpha;
      }
      li *= alpha;
      mi = mnew;
    }
    floatx4 ps4 = {};
    #pragma unroll
    for (int c = 0; c < 4; c++) {
      const floatx4 e4 = sv4[c] - mi;
      floatx4 p4;
      bf16x4 pk;
      #pragma unroll
      for (int e = 0; e < 4; e++) {
        p4[e] = __expf(e4[e]);
        pk[e] = (bf16_t)p4[e];
      }
      ps4 += p4;
      *(bf16x4*)(myP + r16 * 72 + c * 16 + quad * 4) = pk;
    }
    float psum = (ps4[0] + ps4[1]) + (ps4[2] + ps4[3]);
    psum += __shfl_xor(psum, 16);
    psum += __shfl_xor(psum, 32);
    li += psum;

    bf16x8 pf0 = *(const bf16x8*)(myP + r16 * 72 + quad * 8);
    bf16x8 pf1 = *(const bf16x8*)(myP + r16 * 72 + 32 + quad * 8);
    #pragma unroll
    for (int t4 = 0; t4 < 4; t4++) {
      const int rbase = (t4 * 16 + r16) * 64;
      bf16x8 vf0 = *(const bf16x8*)(&lV[rbase + sl0]);
      bf16x8 vf1 = *(const bf16x8*)(&lV[rbase + sl1]);
      of[t4] = __builtin_amdgcn_mfma_f32_16x16x32_bf16(vf0, pf0, of[t4], 0, 0, 0);
      of[t4] = __builtin_amdgcn_mfma_f32_16x16x32_bf16(vf1, pf1, of[t4], 0, 0, 0);
    }
  }
  // epilogue: lane owns O^T[d=t4*16+quad*4..+3][q=r16]; fp16 partials.
  const size_t idx = (size_t)s * ROWSc + (size_t)bh * Lc + q0 + r16;
  #pragma unroll
  for (int t4 = 0; t4 < 4; t4++) {
    half4 o;
    #pragma unroll
    for (int reg = 0; reg < 4; reg++) o[reg] = (half_t)of[t4][reg];
    *(half4*)(Op + idx * 64 + t4 * 16 + quad * 4) = o;
  }
  if (lane < 16) { Mp[idx] = mi; Lp[idx] = li; }
}

// ---------------- merge partials -> AO (bf16, (B,L,E)) ----------------
__global__ __launch_bounds__(256) void k_merge(
    const half_t* __restrict__ Op, const float* __restrict__ Mp,
    const float* __restrict__ Lp, bf16_t* __restrict__ AO, int nS) {
  const int t = blockIdx.x * 256 + threadIdx.x;
  const int row = t >> 4, dc = (t & 15) * 4;
  float mmax = -1e30f;
  for (int s = 0; s < nS; s++) mmax = fmaxf(mmax, Mp[(size_t)s * ROWSc + row]);
  float L = 0.f;
  float o0 = 0.f, o1 = 0.f, o2 = 0.f, o3 = 0.f;
  for (int s = 0; s < nS; s++) {
    const size_t idx = (size_t)s * ROWSc + row;
    const float w = __expf(Mp[idx] - mmax);
    L += w * Lp[idx];
    const half4 v = *(const half4*)(Op + idx * 64 + dc);
    o0 += w * (float)v[0]; o1 += w * (float)v[1];
    o2 += w * (float)v[2]; o3 += w * (float)v[3];
  }
  const float inv = (L > 0.f) ? __builtin_amdgcn_rcpf(L) : 0.f;
  const int bh = row >> 11, l = row & 2047;
  const int b = bh / Hc, h = bh - b * Hc;
  bf16x4 o;
  o[0] = (bf16_t)(o0 * inv); o[1] = (bf16_t)(o1 * inv);
  o[2] = (bf16_t)(o2 * inv); o[3] = (bf16_t)(o3 * inv);
  *(bf16x4*)(AO + ((size_t)(b * Lc + l)) * Ec + h * 64 + dc) = o;
}

// ---------------- launch ----------------

extern "C" void kernel_launch(void* const* d_in, const int* in_sizes, int n_in,
                              void* d_out, int out_size, void* d_ws, size_t ws_size,
                              hipStream_t stream) {
  const float* x    = (const float*)d_in[0];
  const int*   mask = (const int*)d_in[1];
  const float* Wqkv = (const float*)d_in[2];
  const float* bqkv = (const float*)d_in[3];
  const float* Wout = (const float*)d_in[4];
  const float* bout = (const float*)d_in[5];
  float* out = (float*)d_out;

  auto al = [](size_t v) { return (v + 255) & ~(size_t)255; };
  char* ws = (char*)d_ws;
  size_t off = 0;
  auto carve = [&](size_t bytes) -> char* {
    char* p = ws + off;
    off += al(bytes);
    return p;
  };
  // persistent across phases
  bf16_t* WoT = (bf16_t*)carve((size_t)Ec * Ec * 2);
  bf16_t* Qb  = (bf16_t*)carve((size_t)ROWSc * Dc * 2);
  bf16_t* Kb  = (bf16_t*)carve((size_t)ROWSc * Dc * 2);
  bf16_t* VTb = (bf16_t*)carve((size_t)ROWSc * Dc * 2);
  bf16_t* AOb = (bf16_t*)carve((size_t)Mc * Ec * 2);
  float*  qsq = (float*)carve((size_t)ROWSc * 4);
  float*  ksq = (float*)carve((size_t)ROWSc * 4);
  const size_t uni = off;
  // phase-1 view (dead after k_gemm_qkv): xb, WqT
  bf16_t* xb  = (bf16_t*)(ws + uni);
  bf16_t* WqT = (bf16_t*)(ws + uni + al((size_t)Mc * Ec * 2));
  const size_t ph1 = al((size_t)Mc * Ec * 2) + al((size_t)N3c * Ec * 2);
  // phase-2 view (k_attn -> k_merge): Op (fp16), Mp, Lp
  auto ph2 = [&](int S) {
    return al((size_t)S * ROWSc * Dc * 2) + 2 * al((size_t)S * ROWSc * 4);
  };
  int S = 2;
  for (int cand : {4, 3}) {
    size_t need = uni + (ph1 > ph2(cand) ? ph1 : ph2(cand));
    if (need <= ws_size) { S = cand; break; }
  }
  half_t* Op = (half_t*)(ws + uni);
  float*  Mp = (float*)(ws + uni + al((size_t)S * ROWSc * Dc * 2));
  float*  Lp = (float*)(ws + uni + al((size_t)S * ROWSc * Dc * 2) + al((size_t)S * ROWSc * 4));
  (void)in_sizes; (void)n_in; (void)out_size;

  k_prep<<<NBCVT + NBTC1 + NBTC2, 256, 0, stream>>>(x, xb, Wqkv, WqT, Wout, WoT);
  k_gemm_qkv<<<dim3(N3c / 128, Mc / 128), 256, 0, stream>>>(xb, WqT, bqkv, Qb, Kb, VTb);
  k_sq<<<ROWSc / 256, 256, 0, stream>>>(Qb, Kb, mask, qsq, ksq);
  k_attn<<<dim3(ROWSc / 64, S), 256, 0, stream>>>(Qb, Kb, VTb, qsq, ksq, Op, Mp, Lp, S);
  k_merge<<<ROWSc * 16 / 256, 256, 0, stream>>>(Op, Mp, Lp, AOb, S);
  k_gemm_out<<<dim3(Ec / 128, Mc / 128), 256, 0, stream>>>(AOb, WoT, bout, out);
}